// Round 1
// baseline (201.988 us; speedup 1.0000x reference)
//
#include <hip/hip_runtime.h>

// Problem constants (from setup_inputs: Y is 16384 x 2048 fp32, row-major)
#define NROWS 16384
#define D     2048
#define D4    (D / 4)            // 512 float4 per row
#define YBLOCKS 256              // row-stripe blocks
#define ROWS_PER_BLOCK (NROWS / YBLOCKS)  // 64

// Kernel 1: per-column sum of squares over a 64-row stripe.
// grid = (2, YBLOCKS), block = 256. Thread covers 4 consecutive columns
// (one float4). Fully coalesced 16B/lane loads. Writes float4 partial
// per thread into P (layout: [yblock][D] floats).
__global__ void __launch_bounds__(256)
colsq_partial(const float4* __restrict__ Y4, float4* __restrict__ P4) {
    const int c4 = blockIdx.x * 256 + threadIdx.x;      // [0, 512)
    const int yb = blockIdx.y;
    const float4* p = Y4 + (size_t)yb * ROWS_PER_BLOCK * D4 + c4;
    float4 acc = make_float4(0.f, 0.f, 0.f, 0.f);
#pragma unroll 8
    for (int r = 0; r < ROWS_PER_BLOCK; ++r) {
        float4 v = p[(size_t)r * D4];
        acc.x += v.x * v.x;
        acc.y += v.y * v.y;
        acc.z += v.z * v.z;
        acc.w += v.w * v.w;
    }
    P4[(size_t)yb * D4 + c4] = acc;
}

// Kernel 2: reduce partials per column, apply |1 - s/n|, sum to scalar.
// grid = 8, block = 256 (one thread per column). Partials are 2MB,
// L2-resident; loads coalesced across lanes for each yb iteration.
__global__ void __launch_bounds__(256)
finalize(const float* __restrict__ P, float* __restrict__ out) {
    const int c = blockIdx.x * 256 + threadIdx.x;       // [0, 2048)
    float s = 0.f;
#pragma unroll 8
    for (int yb = 0; yb < YBLOCKS; ++yb)
        s += P[yb * D + c];
    float v = fabsf(1.0f - s * (1.0f / (float)NROWS));
    // wave64 reduce
#pragma unroll
    for (int off = 32; off; off >>= 1)
        v += __shfl_down(v, off, 64);
    __shared__ float lds[4];
    const int lane = threadIdx.x & 63;
    const int wv   = threadIdx.x >> 6;
    if (lane == 0) lds[wv] = v;
    __syncthreads();
    if (threadIdx.x == 0) {
        float b = lds[0] + lds[1] + lds[2] + lds[3];
        atomicAdd(out, b);
    }
}

extern "C" void kernel_launch(void* const* d_in, const int* in_sizes, int n_in,
                              void* d_out, int out_size, void* d_ws, size_t ws_size,
                              hipStream_t stream) {
    const float4* Y4 = (const float4*)d_in[0];
    float* out = (float*)d_out;
    float* P   = (float*)d_ws;     // 256 * 2048 floats = 2 MB partials

    // d_out is poisoned 0xAA before every timed launch; zero it (atomicAdd target).
    hipMemsetAsync(out, 0, sizeof(float), stream);

    colsq_partial<<<dim3(2, YBLOCKS), 256, 0, stream>>>(Y4, (float4*)d_ws);
    finalize<<<dim3(8), 256, 0, stream>>>(P, out);
}